// Round 2
// baseline (259.450 us; speedup 1.0000x reference)
//
#include <hip/hip_runtime.h>
#include <hip/hip_bf16.h>

#define N_NODES 200000
#define KDIM 27
#define C_IN 32
#define C_OUT 32
// chunk-major data layout: 4 chunks of 8 channels, each region 200000*16B = 3.2 MB (< 4MB L2/XCD)

typedef __bf16 bf16x8 __attribute__((ext_vector_type(8)));
typedef float floatx4 __attribute__((ext_vector_type(4)));
typedef float float4_t __attribute__((ext_vector_type(4)));

__device__ inline bf16x8 zero_bf16x8() {
    bf16x8 z;
#pragma unroll
    for (int i = 0; i < 8; ++i) z[i] = (__bf16)0.0f;
    return z;
}

// Kernel 1: fp32 [N][32] -> bf16 chunk-major [4][N][8].
// One thread per node: reads 128B contiguous, writes 4x16B (coalesced per region).
__global__ __launch_bounds__(256) void convert_data_kernel(
    const float* __restrict__ src, __bf16* __restrict__ dst) {
    int i = blockIdx.x * 256 + threadIdx.x;
    if (i >= N_NODES) return;
    const float4_t* s = (const float4_t*)(src + (size_t)i * 32);
    float4_t v[8];
#pragma unroll
    for (int j = 0; j < 8; ++j) v[j] = s[j];
#pragma unroll
    for (int c = 0; c < 4; ++c) {
        bf16x8 o;
        o[0] = (__bf16)v[2*c][0]; o[1] = (__bf16)v[2*c][1];
        o[2] = (__bf16)v[2*c][2]; o[3] = (__bf16)v[2*c][3];
        o[4] = (__bf16)v[2*c+1][0]; o[5] = (__bf16)v[2*c+1][1];
        o[6] = (__bf16)v[2*c+1][2]; o[7] = (__bf16)v[2*c+1][3];
        ((bf16x8*)dst)[(size_t)c * N_NODES + i] = o;
    }
}

// Kernel 2: pack weights into B-fragment layout for the (tap,chunk) K-mapping.
// Group g = (c*7 + t)*2 + tt  (c: chunk 0..3, t: tap-group 0..6, tt: o-half 0..1)
// wp[(g*64 + lane)*8 + j] = w[kk=4t+(lane>>4)][ch=8c+j][o=tt*16+(lane&15)], 0 if kk>=27
__global__ __launch_bounds__(256) void pack_weights_kernel(
    const float* __restrict__ w, __bf16* __restrict__ wp) {
    int id = blockIdx.x * 256 + threadIdx.x;   // 56*64*8 = 28672 threads (112 blocks)
    if (id >= 56 * 64 * 8) return;
    int j = id & 7;
    int lane = (id >> 3) & 63;
    int g = id >> 9;
    int tt = g & 1;
    int rest = g >> 1;
    int t = rest % 7;
    int c = rest / 7;
    int kk = 4 * t + (lane >> 4);
    int ch = 8 * c + j;
    int o  = tt * 16 + (lane & 15);
    wp[id] = (kk < KDIM) ? (__bf16)w[((size_t)kk * C_IN + ch) * C_OUT + o] : (__bf16)0.0f;
}

// Kernel 3: gather + MFMA. One wave = 32 nodes x 32 outputs.
// K-slot mapping: quad q supplies tap kk=4t+q, channels [8c, 8c+8).
// A-frag: A[m=lane&15][k=q*8+j]; C/D: col=lane&15, row=q*4+reg.
__global__ __launch_bounds__(128) void octconv_main_kernel(
    const int* __restrict__ neigh, const __bf16* __restrict__ data_q,
    const __bf16* __restrict__ wpack, float* __restrict__ out) {
    int tid  = threadIdx.x;
    int wave = tid >> 6;
    int lane = tid & 63;
    int node_base = (blockIdx.x * 2 + wave) * 32;   // 3125 blocks * 2 waves * 32 = 200000 exact
    int r16 = lane & 15;
    int q   = lane >> 4;

    int n0 = node_base + r16;
    int n1 = n0 + 16;

    // Preload this lane's 14 neighbor indices (taps kk = 4t+q), non-temporal.
    const int* np0 = neigh + (size_t)n0 * KDIM + q;
    const int* np1 = neigh + (size_t)n1 * KDIM + q;
    int it0[7], it1[7];
#pragma unroll
    for (int t = 0; t < 6; ++t) {
        it0[t] = __builtin_nontemporal_load(np0 + 4 * t);
        it1[t] = __builtin_nontemporal_load(np1 + 4 * t);
    }
    // t=6: kk = 24+q; q==3 -> kk=27 (padding slot, B is zero there)
    it0[6] = (q == 3) ? -1 : __builtin_nontemporal_load(np0 + 24);
    it1[6] = (q == 3) ? -1 : __builtin_nontemporal_load(np1 + 24);

    floatx4 acc00 = {0.f, 0.f, 0.f, 0.f};
    floatx4 acc01 = {0.f, 0.f, 0.f, 0.f};
    floatx4 acc10 = {0.f, 0.f, 0.f, 0.f};
    floatx4 acc11 = {0.f, 0.f, 0.f, 0.f};

    const bf16x8* wp8 = (const bf16x8*)wpack;

    for (int c = 0; c < 4; ++c) {
        const __bf16* region = data_q + (size_t)c * N_NODES * 8;
#pragma unroll
        for (int t = 0; t < 7; ++t) {
            int i0 = it0[t];
            int i1 = it1[t];
            bf16x8 a0 = zero_bf16x8();
            bf16x8 a1 = zero_bf16x8();
            if (i0 >= 0) a0 = *(const bf16x8*)(region + ((size_t)i0 << 3));
            if (i1 >= 0) a1 = *(const bf16x8*)(region + ((size_t)i1 << 3));
            int gb = ((c * 7 + t) * 2) * 64 + lane;
            bf16x8 b0 = wp8[gb];
            bf16x8 b1 = wp8[gb + 64];
            acc00 = __builtin_amdgcn_mfma_f32_16x16x32_bf16(a0, b0, acc00, 0, 0, 0);
            acc01 = __builtin_amdgcn_mfma_f32_16x16x32_bf16(a0, b1, acc01, 0, 0, 0);
            acc10 = __builtin_amdgcn_mfma_f32_16x16x32_bf16(a1, b0, acc10, 0, 0, 0);
            acc11 = __builtin_amdgcn_mfma_f32_16x16x32_bf16(a1, b1, acc11, 0, 0, 0);
        }
    }

    // Epilogue: C/D row = q*4 + r, col = r16. Non-temporal stores (don't evict L2 chunk).
#pragma unroll
    for (int r = 0; r < 4; ++r) {
        int row = q * 4 + r;
        float* p0 = out + (size_t)(node_base + row) * C_OUT + r16;
        float* p1 = out + (size_t)(node_base + 16 + row) * C_OUT + r16;
        __builtin_nontemporal_store(acc00[r], p0);
        __builtin_nontemporal_store(acc01[r], p0 + 16);
        __builtin_nontemporal_store(acc10[r], p1);
        __builtin_nontemporal_store(acc11[r], p1 + 16);
    }
}

extern "C" void kernel_launch(void* const* d_in, const int* in_sizes, int n_in,
                              void* d_out, int out_size, void* d_ws, size_t ws_size,
                              hipStream_t stream) {
    const float* data    = (const float*)d_in[0];   // [N, C_IN] fp32
    const float* weights = (const float*)d_in[1];   // [K, C_IN, C_OUT] fp32
    const int*   neigh   = (const int*)d_in[2];     // [N, K] int32
    float*       out     = (float*)d_out;           // [N, C_OUT] fp32

    __bf16* data_q = (__bf16*)d_ws;                                     // 12.8 MB
    __bf16* wpack  = (__bf16*)((char*)d_ws + (size_t)N_NODES * C_IN * 2); // 57 KB

    hipLaunchKernelGGL(convert_data_kernel, dim3((N_NODES + 255) / 256),
                       dim3(256), 0, stream, data, data_q);
    hipLaunchKernelGGL(pack_weights_kernel, dim3((56 * 64 * 8 + 255) / 256),
                       dim3(256), 0, stream, weights, wpack);
    hipLaunchKernelGGL(octconv_main_kernel, dim3(N_NODES / 64), dim3(128), 0, stream,
                       neigh, data_q, wpack, out);
}